// Round 10
// baseline (31.366 us; speedup 1.0000x reference)
//
#include <hip/hip_runtime.h>
#include <hip/hip_fp16.h>

// Problem geometry (fixed by the reference)
#define NROWS   32768      // out_features N
#define KTOT    8192       // in_features K
#define KP      1024       // packed bytes per row (each stored as one int32 on device)
#define GROUPS  64         // scale groups per row (K/128)

#define SLICE_W 1024       // weights per LUT slice
#define SLICE_I 128        // int32 elements per slice per row (512 B)
#define NSLICES 8
#define BLK     512        // 8 waves
#define ROWS_PER_BLK 64
#define NBLOCKS (NROWS / ROWS_PER_BLK)   // 512 = 2 blocks/CU
#define LUTW    136        // 128 entries + 8 pad

// ---------------------------------------------------------------------------
// Fused single kernel: one block = 64 rows x full K, looping over 8 slices
// with per-slice rebuild of the sign-symmetric fp16 byte-LUT (proven in R9:
// 1 ds_read_u16 + ~6 VALU per packed byte).
//
//  - packed: each block reads ONE contiguous 256 KB region (64 rows x 4 KB)
//  - scales: one coalesced 16 KB tile -> fp16 in LDS, applied in-register
//  - no workspace, no second kernel
//  - next slice's 4 int4 loads issued BEFORE the end-of-slice barrier: the
//    compiler's vmcnt(0) drain at the barrier completes them "for free"
// ---------------------------------------------------------------------------
__global__ __launch_bounds__(BLK, 4)
void bitlin_fused(const float* __restrict__ x,
                  const int* __restrict__ packed,
                  const float* __restrict__ scales,
                  float* __restrict__ out)
{
    __shared__ __align__(16) ushort lutU[SLICE_I * LUTW];   // 34 KB
    __shared__ ushort s_sh[ROWS_PER_BLK][66];               // 8.25 KB fp16 scales

    const int tid     = threadIdx.x;
    const int rowBase = blockIdx.x * ROWS_PER_BLK;
    const int lane = tid & 63;
    const int wave = tid >> 6;        // 0..7, owns 8 rows
    const int sub  = lane & 31;       // int4 index within a 512 B row-slice
    const int rsub = lane >> 5;       // row-within-2 per iteration

    const int4* __restrict__ p4 = (const int4*)packed;

    // ---- prologue: issue slice-0 packed loads first (in flight during staging)
    int4 vbuf[4];
#pragma unroll
    for (int t = 0; t < 4; ++t) {
        const int rl = wave * 8 + t * 2 + rsub;
        vbuf[t] = p4[(size_t)(rowBase + rl) * (KP / 4) + sub];
    }

    // ---- stage scales: 64 rows x 64 groups, coalesced fp32 -> fp16 LDS
    {
        const float4* s4 = (const float4*)(scales + (size_t)rowBase * GROUPS);
#pragma unroll
        for (int i = 0; i < 2; ++i) {
            const int idx = i * 512 + tid;        // 1024 float4 in the tile
            const float4 v = s4[idx];
            const int r = idx >> 4;               // 16 float4 per row
            const int c = (idx & 15) * 4;
            s_sh[r][c + 0] = __half_as_ushort(__float2half_rn(v.x));
            s_sh[r][c + 1] = __half_as_ushort(__float2half_rn(v.y));
            s_sh[r][c + 2] = __half_as_ushort(__float2half_rn(v.z));
            s_sh[r][c + 3] = __half_as_ushort(__float2half_rn(v.w));
        }
    }
    // (s_sh visibility covered by the first in-loop barrier)

    float acc[4] = {0.f, 0.f, 0.f, 0.f};

    for (int s = 0; s < NSLICES; ++s) {
        // ---- build LUT for slice s (R9 build, verbatim): thread owns
        // (pos = tid>>2, oct = tid&3 -> idx bits 5,6); 5-bit Gray walk.
        {
            const int pos = tid >> 2;          // 0..127 (8 weights each)
            const int oct = tid & 3;
            float xs[8];
#pragma unroll
            for (int i = 0; i < 8; ++i) xs[i] = x[s * SLICE_W + pos * 8 + i];
            float e = -xs[0] - xs[1] - xs[2] - xs[3] - xs[4]
                    + ((oct & 1) ? xs[5] : -xs[5])
                    + ((oct & 2) ? xs[6] : -xs[6])
                    - xs[7];
            const float t0 = 2.f*xs[0], t1 = 2.f*xs[1], t2 = 2.f*xs[2],
                        t3 = 2.f*xs[3], t4 = 2.f*xs[4];
            ushort h[32];                      // constant-indexed -> registers
#define HSET(i) h[i] = __half_as_ushort(__float2half_rn(e))
            HSET(0);
            e += t0; HSET(1);  e += t1; HSET(3);  e -= t0; HSET(2);
            e += t2; HSET(6);  e += t0; HSET(7);  e -= t1; HSET(5);  e -= t0; HSET(4);
            e += t3; HSET(12); e += t0; HSET(13); e += t1; HSET(15); e -= t0; HSET(14);
            e -= t2; HSET(10); e += t0; HSET(11); e -= t1; HSET(9);  e -= t0; HSET(8);
            e += t4; HSET(24); e += t0; HSET(25); e += t1; HSET(27); e -= t0; HSET(26);
            e += t2; HSET(30); e += t0; HSET(31); e -= t1; HSET(29); e -= t0; HSET(28);
            e -= t3; HSET(20); e += t0; HSET(21); e += t1; HSET(23); e -= t0; HSET(22);
            e -= t2; HSET(18); e += t0; HSET(19); e -= t1; HSET(17); e -= t0; HSET(16);
#undef HSET
#define PK(a,b) ((unsigned)h[a] | ((unsigned)h[b] << 16))
            uint4* dst = (uint4*)&lutU[pos * LUTW + oct * 32];
            dst[0] = make_uint4(PK( 0, 1), PK( 2, 3), PK( 4, 5), PK( 6, 7));
            dst[1] = make_uint4(PK( 8, 9), PK(10,11), PK(12,13), PK(14,15));
            dst[2] = make_uint4(PK(16,17), PK(18,19), PK(20,21), PK(22,23));
            dst[3] = make_uint4(PK(24,25), PK(26,27), PK(28,29), PK(30,31));
#undef PK
        }
        __syncthreads();      // LUT (and, on s==0, s_sh) ready

        // ---- prefetch next slice's packed data (drained-complete at the
        // end-of-slice barrier, so slice s+1 starts with data ready)
        int4 vnext[4];
        if (s < NSLICES - 1) {
#pragma unroll
            for (int t = 0; t < 4; ++t) {
                const int rl = wave * 8 + t * 2 + rsub;
                vnext[t] = p4[(size_t)(rowBase + rl) * (KP / 4)
                              + (s + 1) * (SLICE_I / 4) + sub];
            }
        }

        // ---- consume this slice: 4 iterations x 2 rows per wave
        const ushort* lrow = &lutU[(sub * 4) * LUTW];
#pragma unroll
        for (int t = 0; t < 4; ++t) {
            const int rl = wave * 8 + t * 2 + rsub;
            const int bb[4] = { vbuf[t].x & 255, vbuf[t].y & 255,
                                vbuf[t].z & 255, vbuf[t].w & 255 };
            float part = 0.f;
#pragma unroll
            for (int c = 0; c < 4; ++c) {
                const int b   = bb[c];
                const int m   = b >> 7;                  // 0 or 1
                const int idx = (b ^ (-m)) & 127;        // complement if bit7
                unsigned u = lrow[c * LUTW + idx];
                u ^= (unsigned)(m << 15);                // fp16 sign flip
                part += __half2float(__ushort_as_half((ushort)u));
            }
            // 4-lane butterfly -> group partial (all 4 lanes hold it)
            part += __shfl_xor(part, 1);
            part += __shfl_xor(part, 2);
            // scale this group, then sum the 8 groups of the slice
            const float sc =
                __half2float(__ushort_as_half(s_sh[rl][s * 8 + (sub >> 2)]));
            float v = part * sc;
            v += __shfl_xor(v, 4);
            v += __shfl_xor(v, 8);
            v += __shfl_xor(v, 16);
            acc[t] += v;
        }
        __syncthreads();      // all waves done reading lutU before rebuild

        if (s < NSLICES - 1) {
#pragma unroll
            for (int t = 0; t < 4; ++t) vbuf[t] = vnext[t];
        }
    }

    // ---- epilogue: lane sub==0 of each row-half writes the row result
    if (sub == 0) {
#pragma unroll
        for (int t = 0; t < 4; ++t)
            out[rowBase + wave * 8 + t * 2 + rsub] = acc[t];
    }
}

extern "C" void kernel_launch(void* const* d_in, const int* in_sizes, int n_in,
                              void* d_out, int out_size, void* d_ws, size_t ws_size,
                              hipStream_t stream)
{
    (void)d_ws; (void)ws_size; (void)n_in; (void)in_sizes; (void)out_size;
    const float* x      = (const float*)d_in[0];
    const int*   packed = (const int*)d_in[1];
    const float* scales = (const float*)d_in[2];

    bitlin_fused<<<dim3(NBLOCKS), dim3(BLK), 0, stream>>>(
        x, packed, scales, (float*)d_out);
}